// Round 1
// baseline (1050.630 us; speedup 1.0000x reference)
//
#include <hip/hip_runtime.h>
#include <stdint.h>
#include <stddef.h>

#define NL   512                 // transform size
#define NF   257                 // number of filters (1 + 16*16)
#define NNE  (NL*NL)             // elements per plane
#define TWO_PI_OVER_N 0.012271846303085130f   // 2*pi/512

// ---------------- helpers ----------------
__device__ __forceinline__ unsigned short f2bf(float x) {   // fp32 -> bf16 RNE
  unsigned int u = __float_as_uint(x);
  u += 0x7fffu + ((u >> 16) & 1u);
  return (unsigned short)(u >> 16);
}

typedef __attribute__((ext_vector_type(8))) short bf16x8;
typedef __attribute__((ext_vector_type(4))) float f32x4;

// ---------------- pass 1: row IFFTs (one row per block) ----------------
// in[c] = (x_hat[r,c]) * (psi[f,r,c]) complex product; 512-pt inverse DFT
// (sign +, unnormalized) along c via in-place radix-2 DIF -> bit-reversed c
// order (harmless: spatial stats are permutation invariant).
__global__ __launch_bounds__(256) void pass1_rows(const float* __restrict__ x,
                                                  const float* __restrict__ pr,
                                                  const float* __restrict__ pi,
                                                  float2* __restrict__ W,
                                                  int f0) {
  __shared__ float Xr[NL], Xi[NL];
  __shared__ float2 tw[256];          // tw[k] = exp(+2*pi*i*k/512)
  const int t  = threadIdx.x;
  const int r  = blockIdx.x;
  const int fb = blockIdx.y;
  const int f  = f0 + fb;

  { float s, c; __sincosf((float)t * TWO_PI_OVER_N, &s, &c); tw[t] = make_float2(c, s); }

  const float2* xrow = (const float2*)(x + (size_t)r * (2 * NL));
  const size_t prow = ((size_t)f * NL + r) * NL;
  const int c0 = t, c1 = t + 256;
  {
    float2 xv = xrow[c0];
    float p0r = pr[prow + c0], p0i = pi[prow + c0];
    Xr[c0] = xv.x * p0r - xv.y * p0i;
    Xi[c0] = xv.x * p0i + xv.y * p0r;
    float2 xw = xrow[c1];
    float p1r = pr[prow + c1], p1i = pi[prow + c1];
    Xr[c1] = xw.x * p1r - xw.y * p1i;
    Xi[c1] = xw.x * p1i + xw.y * p1r;
  }
  __syncthreads();

  // 9 in-place DIF stages, half-size h = 256..1
  for (int lh = 8; lh >= 0; --lh) {
    const int h  = 1 << lh;
    const int k  = t & (h - 1);
    const int i0 = ((t >> lh) << (lh + 1)) + k;
    const int i1 = i0 + h;
    float ar = Xr[i0], ai = Xi[i0], br = Xr[i1], bi = Xi[i1];
    float2 w = tw[k << (8 - lh)];
    Xr[i0] = ar + br;  Xi[i0] = ai + bi;
    float dr = ar - br, di = ai - bi;
    Xr[i1] = w.x * dr - w.y * di;
    Xi[i1] = w.x * di + w.y * dr;
    __syncthreads();
  }

  float2* Wrow = W + ((size_t)fb * NL + r) * NL;
  Wrow[c0] = make_float2(Xr[c0], Xi[c0]);
  Wrow[c1] = make_float2(Xr[c1], Xi[c1]);
}

// ---------------- pass 2: column IFFTs, 8 columns per block ----------------
// Loads a 512x8 column tile (64B-per-row fully-used lines), in-place DIF per
// column in LDS, modulus with 1/N^2 scaling + eps, store bf16 m plane in
// (c,r) order (bit-reversed r slots — consistent permutation).
#define PADC 520   // per-column LDS stride (520%32=8 banks -> <=2-way conflicts)
__global__ __launch_bounds__(256) void pass2_cols(const float2* __restrict__ W,
                                                  unsigned short* __restrict__ m,
                                                  int f0) {
  __shared__ float Xr[8 * PADC], Xi[8 * PADC];
  __shared__ float2 tw[256];
  const int t    = threadIdx.x;
  const int tile = blockIdx.x;     // 0..63
  const int fb   = blockIdx.y;
  const int f    = f0 + fb;
  const int c0   = tile * 8;

  { float s, c; __sincosf((float)t * TWO_PI_OVER_N, &s, &c); tw[t] = make_float2(c, s); }

  const float2* Wp = W + (size_t)fb * NNE;
  for (int it = 0; it < 8; ++it) {            // 2 complex per thread per iter
    int idx = it * 256 + t;
    int r = idx >> 2, cp = idx & 3;
    float4 v = *(const float4*)(Wp + (size_t)r * NL + c0 + cp * 2);
    int cl = cp * 2;
    Xr[cl * PADC + r] = v.x;        Xi[cl * PADC + r] = v.y;
    Xr[(cl + 1) * PADC + r] = v.z;  Xi[(cl + 1) * PADC + r] = v.w;
  }
  __syncthreads();

  const int col = t >> 5;          // 8 columns x 32 threads
  const int b0  = t & 31;
  const int cb  = col * PADC;
  for (int lh = 8; lh >= 0; --lh) {
    const int h = 1 << lh;
    for (int u = 0; u < 8; ++u) {  // 8 butterflies per thread per stage
      int b  = b0 + u * 32;
      int k  = b & (h - 1);
      int i0 = cb + (((b >> lh) << (lh + 1)) + k);
      int i1 = i0 + h;
      float ar = Xr[i0], ai = Xi[i0], br = Xr[i1], bi = Xi[i1];
      float2 w = tw[k << (8 - lh)];
      Xr[i0] = ar + br;  Xi[i0] = ai + bi;
      float dr = ar - br, di = ai - bi;
      Xr[i1] = w.x * dr - w.y * di;
      Xi[i1] = w.x * di + w.y * dr;
    }
    __syncthreads();
  }

  const float inv = 1.0f / (float)NNE;        // ifft2 normalization
  unsigned short* mp = m + (size_t)f * NNE + (size_t)c0 * NL;
  for (int it = 0; it < 16; ++it) {
    int idx = it * 256 + t;
    int cl = idx >> 9, r = idx & 511;
    float re = Xr[cl * PADC + r] * inv;
    float im = Xi[cl * PADC + r] * inv;
    float mm = sqrtf(re * re + im * im + 1e-8f);
    mp[cl * NL + r] = f2bf(mm);
  }
}

// ---------------- Gram kernel: 16x16 plane-Gram per group via MFMA ----------
// groups 0..15  : scale j  -> planes p[k=0..15, j]   (E2 diag + C1 pairs)
// groups 16..31 : orient k -> planes p[k, j=0..15]   (C2 pairs)
// A-frag == B-frag (same lane data) gives C = P*P^T directly.
__global__ __launch_bounds__(256) void gram_kernel(const unsigned short* __restrict__ m,
                                                   float* __restrict__ G) {
  const int chunk = blockIdx.x;     // 0..31
  const int g     = blockIdx.y;     // 0..31
  const int wave  = threadIdx.x >> 6;
  const int lane  = threadIdx.x & 63;
  const int mrow  = lane & 15;
  const int quad  = lane >> 4;
  const int pidx  = (g < 16) ? (1 + mrow * 16 + g) : (1 + (g - 16) * 16 + mrow);
  const unsigned short* plane = m + (size_t)pidx * NNE;
  const int base0 = chunk * 8192 + wave * 2048 + quad * 8;

  f32x4 acc = {0.f, 0.f, 0.f, 0.f};
#pragma unroll 4
  for (int it = 0; it < 64; ++it) {
    bf16x8 frag = *(const bf16x8*)(plane + base0 + it * 32);
    acc = __builtin_amdgcn_mfma_f32_16x16x32_bf16(frag, frag, acc, 0, 0, 0);
  }
  const int colo = lane & 15;
  const int row0 = quad * 4;
#pragma unroll
  for (int rr = 0; rr < 4; ++rr)
    atomicAdd(&G[g * 256 + (row0 + rr) * 16 + colo], acc[rr]);
}

// ---------------- Ea / s0 kernel: dot(plane_f, plane_a) ----------------
__global__ __launch_bounds__(256) void ea_kernel(const unsigned short* __restrict__ m,
                                                 float* __restrict__ EA) {
  const int f = blockIdx.x, chunk = blockIdx.y, t = threadIdx.x;
  const unsigned short* p = m + (size_t)f * NNE + chunk * 16384;
  const unsigned short* a = m + chunk * 16384;
  float acc = 0.f;
  for (int it = 0; it < 8; ++it) {
    int off = (it * 256 + t) * 8;
    uint4 up = *(const uint4*)(p + off);
    uint4 ua = *(const uint4*)(a + off);
    const unsigned int pw[4] = {up.x, up.y, up.z, up.w};
    const unsigned int aw[4] = {ua.x, ua.y, ua.z, ua.w};
#pragma unroll
    for (int q = 0; q < 4; ++q) {
      acc += __uint_as_float(pw[q] << 16) * __uint_as_float(aw[q] << 16);
      acc += __uint_as_float(pw[q] & 0xffff0000u) * __uint_as_float(aw[q] & 0xffff0000u);
    }
  }
  __shared__ float red[256];
  red[t] = acc; __syncthreads();
  for (int w = 128; w > 0; w >>= 1) { if (t < w) red[t] += red[t + w]; __syncthreads(); }
  if (t == 0) atomicAdd(&EA[f], red[0]);
}

// ---------------- zero accumulators ----------------
__global__ void zero_acc(float* g) {
  int i = blockIdx.x * 256 + threadIdx.x;
  if (i < 8449) g[i] = 0.f;        // 32*256 Gram + 257 EA floats
}

// ---------------- assemble output in reference ordering ----------------
__global__ __launch_bounds__(256) void assemble_kernel(const float* __restrict__ G,
                                                       const float* __restrict__ EA,
                                                       float* __restrict__ out) {
  const float inv = 1.0f / (float)NNE;
  const int t = threadIdx.x;
  const int i = t >> 4, j = t & 15;
  int base = 1;
  for (int c = 0; c < t; ++c) {
    int ci = c >> 4, cj = c & 15;
    base += 2 + (15 - ci) + (15 - cj);
  }
  if (t == 0) out[0] = EA[0] * inv;                        // s0 = mean(a^2)
  float* o = out + base;
  int n = 0;
  o[n++] = G[j * 256 + i * 16 + i] * inv;                  // E2[i,j]
  o[n++] = EA[1 + i * 16 + j] * inv;                       // Ea[i,j]
  for (int l = i + 1; l < 16; ++l)                         // C1[i, l, j]
    o[n++] = G[j * 256 + i * 16 + l] * inv;
  for (int l = j + 1; l < 16; ++l)                         // C2[i, j, l]
    o[n++] = G[(16 + i) * 256 + j * 16 + l] * inv;
}

// ---------------- launcher ----------------
extern "C" void kernel_launch(void* const* d_in, const int* in_sizes, int n_in,
                              void* d_out, int out_size, void* d_ws, size_t ws_size,
                              hipStream_t stream) {
  const float* x  = (const float*)d_in[0];   // [512,512,2]
  const float* pr = (const float*)d_in[1];   // [257,512,512]
  const float* pi = (const float*)d_in[2];   // [257,512,512]
  float* out = (float*)d_out;
  char* ws = (char*)d_ws;

  // ws layout: m planes (bf16) | Gram acc | EA acc | W batch buffer (complex fp32)
  unsigned short* m = (unsigned short*)ws;                       // 257*512*512*2 B
  const size_t g_off = (size_t)NF * NNE * 2;                     // 134,742,016
  float* G  = (float*)(ws + g_off);                              // 32*256 fp32
  float* EA = (float*)(ws + g_off + 32768);                      // 257 fp32
  const size_t w_off = g_off + 33808;                            // 16-aligned
  float2* W = (float2*)(ws + w_off);

  size_t avail = ws_size > w_off ? ws_size - w_off : 0;
  int BF = (int)(avail / ((size_t)NNE * 8));                     // filters per batch
  if (BF < 1)  BF = 1;
  if (BF > NF) BF = NF;

  zero_acc<<<34, 256, 0, stream>>>(G);

  for (int f0 = 0; f0 < NF; f0 += BF) {
    int bf = NF - f0 < BF ? NF - f0 : BF;
    pass1_rows<<<dim3(512, bf), 256, 0, stream>>>(x, pr, pi, W, f0);
    pass2_cols<<<dim3(64, bf), 256, 0, stream>>>(W, m, f0);
  }

  gram_kernel<<<dim3(32, 32), 256, 0, stream>>>(m, G);
  ea_kernel<<<dim3(NF, 16), 256, 0, stream>>>(m, EA);
  assemble_kernel<<<1, 256, 0, stream>>>(G, EA, out);
}

// Round 2
// 873.227 us; speedup vs baseline: 1.2032x; 1.2032x over previous
//
#include <hip/hip_runtime.h>
#include <hip/hip_fp16.h>
#include <stdint.h>
#include <stddef.h>

#define NL   512                 // transform size
#define NF   257                 // number of filters (1 + 16*16)
#define NNE  (NL*NL)             // elements per plane
#define TWO_PI_OVER_N 0.012271846303085130f   // 2*pi/512

// ---------------- helpers ----------------
__device__ __forceinline__ unsigned short f2bf(float x) {   // fp32 -> bf16 RNE
  unsigned int u = __float_as_uint(x);
  u += 0x7fffu + ((u >> 16) & 1u);
  return (unsigned short)(u >> 16);
}

typedef __attribute__((ext_vector_type(8))) short bf16x8;
typedef __attribute__((ext_vector_type(4))) float f32x4;

// ---------------- pass 1: row IFFTs (one row per block) ----------------
// in[c] = x_hat[r,c] * psi[f,r,c]; 512-pt inverse DFT (sign +, unnormalized)
// along c via in-place radix-2 DIF -> bit-reversed c order (harmless: all
// downstream stats are permutation invariant). Output W stored fp16 complex.
__global__ __launch_bounds__(256) void pass1_rows(const float* __restrict__ x,
                                                  const float* __restrict__ pr,
                                                  const float* __restrict__ pi,
                                                  __half2* __restrict__ W,
                                                  int f0) {
  __shared__ float Xr[NL], Xi[NL];
  __shared__ float2 tw[256];          // tw[k] = exp(+2*pi*i*k/512)
  const int t  = threadIdx.x;
  const int r  = blockIdx.x;
  const int fb = blockIdx.y;
  const int f  = f0 + fb;

  { float s, c; __sincosf((float)t * TWO_PI_OVER_N, &s, &c); tw[t] = make_float2(c, s); }

  const float2* xrow = (const float2*)(x + (size_t)r * (2 * NL));
  const size_t prow = ((size_t)f * NL + r) * NL;
  const int c0 = t, c1 = t + 256;
  {
    float2 xv = xrow[c0];
    float p0r = pr[prow + c0], p0i = pi[prow + c0];
    Xr[c0] = xv.x * p0r - xv.y * p0i;
    Xi[c0] = xv.x * p0i + xv.y * p0r;
    float2 xw = xrow[c1];
    float p1r = pr[prow + c1], p1i = pi[prow + c1];
    Xr[c1] = xw.x * p1r - xw.y * p1i;
    Xi[c1] = xw.x * p1i + xw.y * p1r;
  }
  __syncthreads();

  // 9 in-place DIF stages, half-size h = 256..1
  for (int lh = 8; lh >= 0; --lh) {
    const int h  = 1 << lh;
    const int k  = t & (h - 1);
    const int i0 = ((t >> lh) << (lh + 1)) + k;
    const int i1 = i0 + h;
    float ar = Xr[i0], ai = Xi[i0], br = Xr[i1], bi = Xi[i1];
    float2 w = tw[k << (8 - lh)];
    Xr[i0] = ar + br;  Xi[i0] = ai + bi;
    float dr = ar - br, di = ai - bi;
    Xr[i1] = w.x * dr - w.y * di;
    Xi[i1] = w.x * di + w.y * dr;
    __syncthreads();
  }

  __half2* Wrow = W + ((size_t)fb * NL + r) * NL;
  Wrow[c0] = __floats2half2_rn(Xr[c0], Xi[c0]);
  Wrow[c1] = __floats2half2_rn(Xr[c1], Xi[c1]);
}

// ---------------- pass 2: column IFFTs, 16 columns per block ----------------
// Packed-fp16 in-LDS FFT: complex as __half2, column stride 513 (odd ->
// adjacent columns on disjoint bank parities). Fused radix-4 stages (two
// radix-2 levels per LDS round-trip). Final radix-2 stage fused with the
// modulus (fp32) + bf16 store. m plane layout: (c, bitrev-r) -- a consistent
// permutation across filters, so all spatial statistics are unaffected.
#define P2S 513   // half2 units per column in LDS
__global__ __launch_bounds__(512) void pass2_cols(const __half2* __restrict__ W,
                                                  unsigned short* __restrict__ m,
                                                  int f0) {
  __shared__ __half2 XX[16 * P2S];      // 32832 B
  __shared__ __half2 twA[256], twB[256];
  const int t    = threadIdx.x;
  const int tile = blockIdx.x;          // 0..31
  const int fb   = blockIdx.y;
  const int f    = f0 + fb;
  const int c0   = tile * 16;

  if (t < 256) {
    float s, c; __sincosf((float)t * TWO_PI_OVER_N, &s, &c);
    twA[t] = __floats2half2_rn(c, c);       // (wr, wr)
    twB[t] = __floats2half2_rn(-s, s);      // (-wi, wi)
  }

  // load 512x16 fp16-complex tile (64-B row segments, coalesced)
  const uint4* Wp4 = (const uint4*)(W + (size_t)fb * NNE);
#pragma unroll
  for (int it = 0; it < 4; ++it) {
    int sl = it * 512 + t;
    int r = sl >> 2, g = sl & 3;
    uint4 v = Wp4[r * 128 + (c0 >> 2) + g];
    int cl = g * 4;
    XX[(cl + 0) * P2S + r] = *(__half2*)&v.x;
    XX[(cl + 1) * P2S + r] = *(__half2*)&v.y;
    XX[(cl + 2) * P2S + r] = *(__half2*)&v.z;
    XX[(cl + 3) * P2S + r] = *(__half2*)&v.w;
  }
  __syncthreads();

  const int col = t >> 5;               // 16 columns x 32 threads
  const int b0  = t & 31;
  const int cb  = col * P2S;
  const __half2 mI = __floats2half2_rn(-1.f, 1.f);   // multiply-by-i helper

  // fused radix-4: stages (8,7),(6,5),(4,3),(2,1)
  for (int lh = 8; lh >= 2; lh -= 2) {
    const int hh = 1 << (lh - 1);
#pragma unroll
    for (int q = 0; q < 4; ++q) {
      int p  = b0 + q * 32;             // 128 fused slots per column
      int k  = p & (hh - 1);
      int B  = (p >> (lh - 1)) << (lh + 1);
      int i0 = cb + B + k, i1 = i0 + hh, i2 = i0 + 2 * hh, i3 = i0 + 3 * hh;
      __half2 e0 = XX[i0], e1 = XX[i1], e2 = XX[i2], e3 = XX[i3];
      int kA = k << (8 - lh), kB = k << (9 - lh);
      __half2 aA = twA[kA], bA = twB[kA];
      __half2 aB = twA[kB], bB = twB[kB];
      // level 1 (stage h): pairs (e0,e2) tw^k, (e1,e3) tw^(k+hh) = i*tw^k
      __half2 f0v = __hadd2(e0, e2);
      __half2 f1v = __hadd2(e1, e3);
      __half2 d02 = __hsub2(e0, e2);
      __half2 d13 = __hsub2(e1, e3);
      __half2 f2v = __hfma2(d02, aA, __hmul2(__lowhigh2highlow(d02), bA));
      __half2 t3  = __hfma2(d13, aA, __hmul2(__lowhigh2highlow(d13), bA));
      __half2 f3v = __hmul2(__lowhigh2highlow(t3), mI);   // * i
      // level 2 (stage h/2): pairs (f0,f1) and (f2,f3), both tw^(2k)
      XX[i0] = __hadd2(f0v, f1v);
      __half2 d01 = __hsub2(f0v, f1v);
      XX[i1] = __hfma2(d01, aB, __hmul2(__lowhigh2highlow(d01), bB));
      XX[i2] = __hadd2(f2v, f3v);
      __half2 d23 = __hsub2(f2v, f3v);
      XX[i3] = __hfma2(d23, aB, __hmul2(__lowhigh2highlow(d23), bB));
    }
    __syncthreads();
  }

  // final radix-2 stage (tw = 1) fused with modulus + bf16 store
  const float inv = 1.0f / (float)NNE;
  unsigned int* mp = (unsigned int*)(m + (size_t)f * NNE + (size_t)(c0 + col) * NL);
#pragma unroll
  for (int u = 0; u < 8; ++u) {
    int p = b0 + u * 32;                // 256 pairs per column
    __half2 a = XX[cb + 2 * p], b = XX[cb + 2 * p + 1];
    float2 af = __half22float2(a), bf = __half22float2(b);
    float r0 = (af.x + bf.x) * inv, s0 = (af.y + bf.y) * inv;
    float r1 = (af.x - bf.x) * inv, s1 = (af.y - bf.y) * inv;
    float m0 = sqrtf(r0 * r0 + s0 * s0 + 1e-8f);
    float m1 = sqrtf(r1 * r1 + s1 * s1 + 1e-8f);
    mp[p] = (unsigned int)f2bf(m0) | ((unsigned int)f2bf(m1) << 16);
  }
}

// ---------------- Gram kernel: 16x16 plane-Gram per group via MFMA ----------
// groups 0..15  : scale j  -> planes p[k=0..15, j]   (E2 diag + C1 pairs)
// groups 16..31 : orient k -> planes p[k, j=0..15]   (C2 pairs)
// A-frag == B-frag (same lane data) gives C = P*P^T directly.
__global__ __launch_bounds__(256) void gram_kernel(const unsigned short* __restrict__ m,
                                                   float* __restrict__ G) {
  const int chunk = blockIdx.x;     // 0..31
  const int g     = blockIdx.y;     // 0..31
  const int wave  = threadIdx.x >> 6;
  const int lane  = threadIdx.x & 63;
  const int mrow  = lane & 15;
  const int quad  = lane >> 4;
  const int pidx  = (g < 16) ? (1 + mrow * 16 + g) : (1 + (g - 16) * 16 + mrow);
  const unsigned short* plane = m + (size_t)pidx * NNE;
  const int base0 = chunk * 8192 + wave * 2048 + quad * 8;

  f32x4 acc = {0.f, 0.f, 0.f, 0.f};
#pragma unroll 4
  for (int it = 0; it < 64; ++it) {
    bf16x8 frag = *(const bf16x8*)(plane + base0 + it * 32);
    acc = __builtin_amdgcn_mfma_f32_16x16x32_bf16(frag, frag, acc, 0, 0, 0);
  }
  const int colo = lane & 15;
  const int row0 = quad * 4;
#pragma unroll
  for (int rr = 0; rr < 4; ++rr)
    atomicAdd(&G[g * 256 + (row0 + rr) * 16 + colo], acc[rr]);
}

// ---------------- Ea / s0 kernel: dot(plane_f, plane_a) ----------------
__global__ __launch_bounds__(256) void ea_kernel(const unsigned short* __restrict__ m,
                                                 float* __restrict__ EA) {
  const int f = blockIdx.x, chunk = blockIdx.y, t = threadIdx.x;
  const unsigned short* p = m + (size_t)f * NNE + chunk * 16384;
  const unsigned short* a = m + chunk * 16384;
  float acc = 0.f;
  for (int it = 0; it < 8; ++it) {
    int off = (it * 256 + t) * 8;
    uint4 up = *(const uint4*)(p + off);
    uint4 ua = *(const uint4*)(a + off);
    const unsigned int pw[4] = {up.x, up.y, up.z, up.w};
    const unsigned int aw[4] = {ua.x, ua.y, ua.z, ua.w};
#pragma unroll
    for (int q = 0; q < 4; ++q) {
      acc += __uint_as_float(pw[q] << 16) * __uint_as_float(aw[q] << 16);
      acc += __uint_as_float(pw[q] & 0xffff0000u) * __uint_as_float(aw[q] & 0xffff0000u);
    }
  }
  __shared__ float red[256];
  red[t] = acc; __syncthreads();
  for (int w = 128; w > 0; w >>= 1) { if (t < w) red[t] += red[t + w]; __syncthreads(); }
  if (t == 0) atomicAdd(&EA[f], red[0]);
}

// ---------------- zero accumulators ----------------
__global__ void zero_acc(float* g) {
  int i = blockIdx.x * 256 + threadIdx.x;
  if (i < 8449) g[i] = 0.f;        // 32*256 Gram + 257 EA floats
}

// ---------------- assemble output in reference ordering ----------------
__global__ __launch_bounds__(256) void assemble_kernel(const float* __restrict__ G,
                                                       const float* __restrict__ EA,
                                                       float* __restrict__ out) {
  const float inv = 1.0f / (float)NNE;
  const int t = threadIdx.x;
  const int i = t >> 4, j = t & 15;
  int base = 1;
  for (int c = 0; c < t; ++c) {
    int ci = c >> 4, cj = c & 15;
    base += 2 + (15 - ci) + (15 - cj);
  }
  if (t == 0) out[0] = EA[0] * inv;                        // s0 = mean(a^2)
  float* o = out + base;
  int n = 0;
  o[n++] = G[j * 256 + i * 16 + i] * inv;                  // E2[i,j]
  o[n++] = EA[1 + i * 16 + j] * inv;                       // Ea[i,j]
  for (int l = i + 1; l < 16; ++l)                         // C1[i, l, j]
    o[n++] = G[j * 256 + i * 16 + l] * inv;
  for (int l = j + 1; l < 16; ++l)                         // C2[i, j, l]
    o[n++] = G[(16 + i) * 256 + j * 16 + l] * inv;
}

// ---------------- launcher ----------------
extern "C" void kernel_launch(void* const* d_in, const int* in_sizes, int n_in,
                              void* d_out, int out_size, void* d_ws, size_t ws_size,
                              hipStream_t stream) {
  const float* x  = (const float*)d_in[0];   // [512,512,2]
  const float* pr = (const float*)d_in[1];   // [257,512,512]
  const float* pi = (const float*)d_in[2];   // [257,512,512]
  float* out = (float*)d_out;
  char* ws = (char*)d_ws;

  // ws layout: m planes (bf16) | Gram acc | EA acc | W batch buffer (fp16 complex)
  unsigned short* m = (unsigned short*)ws;                       // 257*512*512*2 B
  const size_t g_off = (size_t)NF * NNE * 2;                     // 134,742,016
  float* G  = (float*)(ws + g_off);                              // 32*256 fp32
  float* EA = (float*)(ws + g_off + 32768);                      // 257 fp32
  const size_t w_off = g_off + 33808;                            // 16-aligned
  __half2* W = (__half2*)(ws + w_off);

  size_t avail = ws_size > w_off ? ws_size - w_off : 0;
  int BF = (int)(avail / ((size_t)NNE * 4));                     // filters per batch
  if (BF < 1)  BF = 1;
  if (BF > NF) BF = NF;

  zero_acc<<<34, 256, 0, stream>>>(G);

  for (int f0 = 0; f0 < NF; f0 += BF) {
    int bf = NF - f0 < BF ? NF - f0 : BF;
    pass1_rows<<<dim3(512, bf), 256, 0, stream>>>(x, pr, pi, W, f0);
    pass2_cols<<<dim3(32, bf), 512, 0, stream>>>(W, m, f0);
  }

  gram_kernel<<<dim3(32, 32), 256, 0, stream>>>(m, G);
  ea_kernel<<<dim3(NF, 16), 256, 0, stream>>>(m, EA);
  assemble_kernel<<<1, 256, 0, stream>>>(G, EA, out);
}